// Round 1
// baseline (7012.452 us; speedup 1.0000x reference)
//
#include <hip/hip_runtime.h>
#include <hip/hip_bf16.h>
#include <cmath>

// Problem constants
#define BB   16
#define LKK  64
#define LQQ  64
#define DD   300
#define HH   512
#define H2   1024
#define G4   2048
#define G8   4096
#define VV   10000

__device__ __forceinline__ float sigmoidf_(float x) { return 1.f / (1.f + expf(-x)); }

// ---------------- reverse source indices for backward encoder ----------------
__global__ void rev_idx_kernel(const int* __restrict__ src, int* __restrict__ rev) {
    int tid = blockIdx.x * blockDim.x + threadIdx.x;
    if (tid < BB * LKK) {
        int b = tid / LKK, t = tid % LKK;
        rev[tid] = src[b * LKK + (LKK - 1 - t)];
    }
}

// ---------------- transpose: out[k*N+n] = in[n*K+k]  (W [N,K] -> Wt [K,N]) ----
__global__ void transpose_kernel(const float* __restrict__ in, float* __restrict__ out,
                                 int N, int K) {
    long tid = (long)blockIdx.x * blockDim.x + threadIdx.x;
    long total = (long)N * K;
    if (tid < total) {
        int n = (int)(tid % N);
        int k = (int)(tid / N);
        out[(long)k * N + n] = in[(long)n * K + k];
    }
}

// ---------------- generic NT GEMM: C[m,n] = sum_k A[m,k]*Bw[n,k] + bias[n] ----
// A row-major [M,K] (or gathered: row m = emb[gidx[m]]); Bw row-major [N,K].
// act: 0=none, 1=tanh. M must be a multiple of 64 (true for all uses: M=1024).
__global__ __launch_bounds__(256)
void gemm_nt_kernel(const float* __restrict__ A, const int* __restrict__ gidx, int lda,
                    const float* __restrict__ Bw, int ldb,
                    const float* __restrict__ bias,
                    float* __restrict__ C, int ldc,
                    int N, int K, int act) {
    __shared__ float As[16][68];
    __shared__ float Bs[16][68];
    int m0 = blockIdx.x * 64;
    int n0 = blockIdx.y * 64;
    int tid = threadIdx.x;
    int tm = tid >> 4, tn = tid & 15;
    float acc[4][4];
#pragma unroll
    for (int i = 0; i < 4; i++)
#pragma unroll
        for (int j = 0; j < 4; j++) acc[i][j] = 0.f;

    int lr = tid >> 2;            // 0..63 : row within tile
    int lk = (tid & 3) * 4;       // 0,4,8,12 : k offset
    long abase;
    {
        int gm = m0 + lr;
        abase = gidx ? (long)gidx[gm] * lda : (long)gm * lda;
    }
    int gn = n0 + lr;
    long bbase = (long)gn * ldb;
    bool bvalid = gn < N;

    for (int k0 = 0; k0 < K; k0 += 16) {
#pragma unroll
        for (int i = 0; i < 4; i++) {
            int k = k0 + lk + i;
            As[lk + i][lr] = (k < K) ? A[abase + k] : 0.f;
            Bs[lk + i][lr] = (bvalid && k < K) ? Bw[bbase + k] : 0.f;
        }
        __syncthreads();
#pragma unroll
        for (int kk = 0; kk < 16; kk++) {
            float a[4], b[4];
#pragma unroll
            for (int i = 0; i < 4; i++) a[i] = As[kk][tm * 4 + i];
#pragma unroll
            for (int j = 0; j < 4; j++) b[j] = Bs[kk][tn * 4 + j];
#pragma unroll
            for (int i = 0; i < 4; i++)
#pragma unroll
                for (int j = 0; j < 4; j++) acc[i][j] += a[i] * b[j];
        }
        __syncthreads();
    }
#pragma unroll
    for (int i = 0; i < 4; i++) {
        int m = m0 + tm * 4 + i;
#pragma unroll
        for (int j = 0; j < 4; j++) {
            int n = n0 + tn * 4 + j;
            if (n < N) {
                float v = acc[i][j] + bias[n];
                if (act == 1) v = tanhf(v);
                C[(long)m * ldc + n] = v;
            }
        }
    }
}

// ---------------- encoder step (fwd+bwd fused) -------------------------------
// Launch t = 0..64. Kernel t computes h_{t-1},c_{t-1} from g_{t-1},c_{t-2}
// (t=0: h=c=0), writes h_{t-1} to enc_out / c to ping-pong, then (t<64)
// computes g_t = xg[:,t] + h_{t-1} @ Whh^T.
// grid: 64 blocks = 2 dirs x 32 col-chunks of 64; 256 threads.
__global__ __launch_bounds__(256)
void enc_step_kernel(const float* __restrict__ xg_f, const float* __restrict__ xg_b,
                     const float* __restrict__ wt_f, const float* __restrict__ wt_b,
                     const float* __restrict__ g_prev, float* __restrict__ g_cur,
                     const float* __restrict__ c_prev, float* __restrict__ c_cur,
                     float* __restrict__ enc_out, int t) {
    int dir = blockIdx.x >> 5;
    int chunk = blockIdx.x & 31;
    int tid = threadIdx.x;
    __shared__ float hs[BB][HH];   // 32 KB

    for (int e = tid; e < BB * HH; e += 256) {
        int b = e >> 9, j = e & (HH - 1);
        float hv, cv;
        if (t == 0) { hv = 0.f; cv = 0.f; }
        else {
            const float* gp = g_prev + (long)(dir * BB + b) * G4;
            float gi = gp[j], gf = gp[j + HH], gg = gp[j + 2 * HH], go = gp[j + 3 * HH];
            float cp = c_prev[(dir * BB + b) * HH + j];
            cv = sigmoidf_(gf) * cp + sigmoidf_(gi) * tanhf(gg);
            hv = sigmoidf_(go) * tanhf(cv);
        }
        hs[b][j] = hv;
        if (chunk == 0) {
            c_cur[(dir * BB + b) * HH + j] = cv;
            if (t >= 1) {
                int s = t - 1;
                int kpos = (dir == 0) ? s : (LKK - 1 - s);  // bwd outputs stored reversed
                enc_out[(long)(b * LKK + kpos) * H2 + dir * HH + j] = hv;
            }
        }
    }
    if (t == LKK) return;
    __syncthreads();

    const float* wt = dir ? wt_b : wt_f;   // [HH][G4]
    const float* xg = dir ? xg_b : xg_f;   // [BB*LKK][G4]
    int n = chunk * 64 + (tid & 63);
    int rb = (tid >> 6) * 4;
    float a0 = 0.f, a1 = 0.f, a2 = 0.f, a3 = 0.f;
#pragma unroll 8
    for (int k = 0; k < HH; k++) {
        float w = wt[(long)k * G4 + n];
        a0 += hs[rb + 0][k] * w;
        a1 += hs[rb + 1][k] * w;
        a2 += hs[rb + 2][k] * w;
        a3 += hs[rb + 3][k] * w;
    }
    g_cur[(long)(dir * BB + rb + 0) * G4 + n] = xg[(long)((rb + 0) * LKK + t) * G4 + n] + a0;
    g_cur[(long)(dir * BB + rb + 1) * G4 + n] = xg[(long)((rb + 1) * LKK + t) * G4 + n] + a1;
    g_cur[(long)(dir * BB + rb + 2) * G4 + n] = xg[(long)((rb + 2) * LKK + t) * G4 + n] + a2;
    g_cur[(long)(dir * BB + rb + 3) * G4 + n] = xg[(long)((rb + 3) * LKK + t) * G4 + n] + a3;
}

// ---------------- decoder step ----------------------------------------------
// grid: 128 blocks = 2 row-halves (8 batches) x 64 col-chunks of 64.
__global__ __launch_bounds__(256)
void dec_step_kernel(const float* __restrict__ xg_d, const float* __restrict__ wt_d,
                     const float* __restrict__ g_prev, float* __restrict__ g_cur,
                     const float* __restrict__ c_prev, float* __restrict__ c_cur,
                     const float* __restrict__ enc_out, const float* __restrict__ enc_c_fin,
                     float* __restrict__ Qout, int t) {
    int rh = blockIdx.x >> 6;
    int chunk = blockIdx.x & 63;
    int tid = threadIdx.x;
    int b0 = rh * 8;
    __shared__ float hs[8][H2];    // 32 KB

    for (int e = tid; e < 8 * H2; e += 256) {
        int br = e >> 10, j = e & (H2 - 1);
        int b = b0 + br;
        float hv, cv;
        if (t == 0) {
            // interleave fwd/bwd final states: h0[b,2j]=hf[b,j], h0[b,2j+1]=hb[b,j]
            int jj = j >> 1;
            if ((j & 1) == 0) {
                hv = enc_out[(long)(b * LKK + (LKK - 1)) * H2 + jj];
                cv = enc_c_fin[(0 * BB + b) * HH + jj];
            } else {
                hv = enc_out[(long)(b * LKK + 0) * H2 + HH + jj];
                cv = enc_c_fin[(1 * BB + b) * HH + jj];
            }
        } else {
            const float* gp = g_prev + (long)b * G8;
            float gi = gp[j], gf = gp[j + H2], gg = gp[j + 2 * H2], go = gp[j + 3 * H2];
            float cp = c_prev[b * H2 + j];
            cv = sigmoidf_(gf) * cp + sigmoidf_(gi) * tanhf(gg);
            hv = sigmoidf_(go) * tanhf(cv);
        }
        hs[br][j] = hv;
        if (chunk == 0) {
            c_cur[b * H2 + j] = cv;
            if (t >= 1) Qout[(long)(b * LQQ + (t - 1)) * H2 + j] = hv;
        }
    }
    if (t == LQQ) return;
    __syncthreads();

    int n = chunk * 64 + (tid & 63);
    int r2 = (tid >> 6) * 2;
    float a0 = 0.f, a1 = 0.f;
#pragma unroll 8
    for (int k = 0; k < H2; k++) {
        float w = wt_d[(long)k * G8 + n];
        a0 += hs[r2 + 0][k] * w;
        a1 += hs[r2 + 1][k] * w;
    }
    int b = b0 + r2;
    g_cur[(long)b * G8 + n]       = xg_d[(long)(b * LQQ + t) * G8 + n] + a0;
    g_cur[(long)(b + 1) * G8 + n] = xg_d[(long)((b + 1) * LQQ + t) * G8 + n] + a1;
}

// ---------------- attention + concat[ctx, Q] ---------------------------------
// grid: B*LQ = 1024 blocks, 256 threads; block = one (b, q).
__global__ __launch_bounds__(256)
void attention_kernel(const float* __restrict__ Qm, const float* __restrict__ Km,
                      const float* __restrict__ Vm, const int* __restrict__ source,
                      float* __restrict__ concatBuf) {
    int b = blockIdx.x >> 6;
    int q = blockIdx.x & 63;
    int tid = threadIdx.x;
    __shared__ float qrow[H2];
    __shared__ float part[LKK][4];
    __shared__ float aw[LKK];

    for (int i = tid; i < H2; i += 256) qrow[i] = Qm[(long)(b * LQQ + q) * H2 + i];
    __syncthreads();

    int k = tid >> 2, p = tid & 3;
    {
        const float* krow = Km + (long)(b * LKK + k) * H2 + p * 256;
        const float* qp = qrow + p * 256;
        float s = 0.f;
#pragma unroll 4
        for (int i = 0; i < 256; i++) s += qp[i] * krow[i];
        part[k][p] = s;
    }
    __syncthreads();
    if (tid < 64) {
        float sc = part[tid][0] + part[tid][1] + part[tid][2] + part[tid][3];
        bool masked = (source[b * LKK + tid] == 0);   // PAD == 0
        float m = masked ? -INFINITY : sc;
#pragma unroll
        for (int o = 32; o >= 1; o >>= 1) m = fmaxf(m, __shfl_xor(m, o, 64));
        float e = masked ? 0.f : expf(sc - m);
        float sum = e;
#pragma unroll
        for (int o = 32; o >= 1; o >>= 1) sum += __shfl_xor(sum, o, 64);
        aw[tid] = e / sum;
    }
    __syncthreads();

    for (int c = tid; c < H2; c += 256) {
        float acc = 0.f;
#pragma unroll 8
        for (int kk = 0; kk < LKK; kk++) acc += aw[kk] * Vm[(long)(b * LKK + kk) * H2 + c];
        long row = (long)(b * LQQ + q) * (2 * H2);
        concatBuf[row + c] = acc;          // ctx
        concatBuf[row + H2 + c] = qrow[c]; // Q
    }
}

// ---------------- host launcher ----------------------------------------------
extern "C" void kernel_launch(void* const* d_in, const int* in_sizes, int n_in,
                              void* d_out, int out_size, void* d_ws, size_t ws_size,
                              hipStream_t stream) {
    const int*   src      = (const int*)  d_in[0];
    const int*   prev     = (const int*)  d_in[1];
    const float* emb      = (const float*)d_in[2];
    const float* enc_f_Wih = (const float*)d_in[3];
    const float* enc_f_Whh = (const float*)d_in[4];
    const float* enc_f_b   = (const float*)d_in[5];
    const float* enc_b_Wih = (const float*)d_in[6];
    const float* enc_b_Whh = (const float*)d_in[7];
    const float* enc_b_b   = (const float*)d_in[8];
    const float* dec_Wih   = (const float*)d_in[9];
    const float* dec_Whh   = (const float*)d_in[10];
    const float* dec_b     = (const float*)d_in[11];
    const float* k_W  = (const float*)d_in[12];
    const float* k_b  = (const float*)d_in[13];
    const float* v_W  = (const float*)d_in[14];
    const float* v_b  = (const float*)d_in[15];
    const float* fc1_W = (const float*)d_in[16];
    const float* fc1_b = (const float*)d_in[17];
    const float* fc2_W = (const float*)d_in[18];
    const float* fc2_b = (const float*)d_in[19];
    float* out = (float*)d_out;

    // workspace layout (floats)
    float* p = (float*)d_ws;
    float* xg_f   = p; p += (long)BB * LKK * G4;        // 2,097,152
    float* xg_b   = p; p += (long)BB * LKK * G4;
    float* xg_d   = p; p += (long)BB * LQQ * G8;        // 4,194,304
    float* wt_f   = p; p += (long)HH * G4;              // 1,048,576
    float* wt_b   = p; p += (long)HH * G4;
    float* wt_d   = p; p += (long)H2 * G8;              // 4,194,304
    float* enc_g  = p; p += 2L * 2 * BB * G4;           // ping-pong, 2 dirs
    float* enc_c  = p; p += 2L * 2 * BB * HH;
    float* enc_out= p; p += (long)BB * LKK * H2;
    float* dec_g  = p; p += 2L * BB * G8;
    float* dec_c  = p; p += 2L * BB * H2;
    float* Qbuf   = p; p += (long)BB * LQQ * H2;
    float* Kbuf   = p; p += (long)BB * LKK * H2;
    float* Vbuf   = p; p += (long)BB * LKK * H2;
    float* concatB= p; p += (long)BB * LQQ * 2 * H2;
    float* fc1out = p; p += (long)BB * LQQ * H2;
    int*   rev    = (int*)p; p += (BB * LKK);

    // 1) reversed source indices
    rev_idx_kernel<<<4, 256, 0, stream>>>(src, rev);

    // 2) transpose Whh weights [N,K] -> [K,N]
    transpose_kernel<<<(G4 * HH + 255) / 256, 256, 0, stream>>>(enc_f_Whh, wt_f, G4, HH);
    transpose_kernel<<<(G4 * HH + 255) / 256, 256, 0, stream>>>(enc_b_Whh, wt_b, G4, HH);
    transpose_kernel<<<(G8 * H2 + 255) / 256, 256, 0, stream>>>(dec_Whh, wt_d, G8, H2);

    // 3) xg precomputes (gathered-embedding GEMMs), M = 1024
    gemm_nt_kernel<<<dim3(16, G4 / 64), 256, 0, stream>>>(emb, src, DD, enc_f_Wih, DD,
                                                          enc_f_b, xg_f, G4, G4, DD, 0);
    gemm_nt_kernel<<<dim3(16, G4 / 64), 256, 0, stream>>>(emb, rev, DD, enc_b_Wih, DD,
                                                          enc_b_b, xg_b, G4, G4, DD, 0);
    gemm_nt_kernel<<<dim3(16, G8 / 64), 256, 0, stream>>>(emb, prev, DD, dec_Wih, DD,
                                                          dec_b, xg_d, G8, G8, DD, 0);

    // 4) encoder recurrence (fwd+bwd fused), t = 0..64
    for (int t = 0; t <= LKK; t++) {
        const float* gp = enc_g + (long)((t + 1) & 1) * 2 * BB * G4;
        float*       gc = enc_g + (long)(t & 1) * 2 * BB * G4;
        const float* cp = enc_c + (long)((t + 1) & 1) * 2 * BB * HH;
        float*       cc = enc_c + (long)(t & 1) * 2 * BB * HH;
        enc_step_kernel<<<64, 256, 0, stream>>>(xg_f, xg_b, wt_f, wt_b, gp, gc, cp, cc,
                                                enc_out, t);
    }
    const float* enc_c_fin = enc_c;  // t=64 wrote ping-pong slot 0

    // 5) K/V projections
    gemm_nt_kernel<<<dim3(16, 16), 256, 0, stream>>>(enc_out, nullptr, H2, k_W, H2,
                                                     k_b, Kbuf, H2, H2, H2, 0);
    gemm_nt_kernel<<<dim3(16, 16), 256, 0, stream>>>(enc_out, nullptr, H2, v_W, H2,
                                                     v_b, Vbuf, H2, H2, H2, 0);

    // 6) decoder recurrence, t = 0..64
    for (int t = 0; t <= LQQ; t++) {
        const float* gp = dec_g + (long)((t + 1) & 1) * BB * G8;
        float*       gc = dec_g + (long)(t & 1) * BB * G8;
        const float* cp = dec_c + (long)((t + 1) & 1) * BB * H2;
        float*       cc = dec_c + (long)(t & 1) * BB * H2;
        dec_step_kernel<<<128, 256, 0, stream>>>(xg_d, wt_d, gp, gc, cp, cc,
                                                 enc_out, enc_c_fin, Qbuf, t);
    }

    // 7) attention -> concat[ctx, Q]
    attention_kernel<<<BB * LQQ, 256, 0, stream>>>(Qbuf, Kbuf, Vbuf, src, concatB);

    // 8) fc1 with tanh
    gemm_nt_kernel<<<dim3(16, 16), 256, 0, stream>>>(concatB, nullptr, 2 * H2, fc1_W, 2 * H2,
                                                     fc1_b, fc1out, H2, H2, 2 * H2, 1);

    // 9) fc2 -> output [1024, 10000]
    gemm_nt_kernel<<<dim3(16, (VV + 63) / 64), 256, 0, stream>>>(fc1out, nullptr, H2, fc2_W, H2,
                                                                 fc2_b, out, VV, VV, H2, 0);
}